// Round 6
// baseline (821.755 us; speedup 1.0000x reference)
//
#include <hip/hip_runtime.h>
#include <math.h>

// Problem constants (reference: B=8, H=W=512)
#define Bsz    8
#define Wdim   512
#define HWv    (512 * 512)       // 262144 = 2^18
#define LOG2HW 18
#define NIMG   16                // {bg(0..7), fg(8..15)}
#define TW     64                // tile width  (one wave row)
#define TH     32                // tile height
#define TPIX   (TW * TH)         // 2048 px per tile
#define NTILE  2048              // (img, tile) pairs: 16 img x 128 tiles
#define LCAP   1024              // max roots per 64x32 tile (checkerboard)
#define NBLK   1024              // coop grid: 4 blocks/CU (HALF capacity: safe)
#define NTHR   256
#define CETOT  (3 * 8 * 32768)   // 786432 8-px CE work items
#define FBCE   3072              // fallback k_ce grid (1 item/thread)

// ws layout (int32 units):
//   [0, 4096)                bar: grid-barrier counters (memset 0 pre-launch)
//   labels[NIMG*HWv]         pixel -> tile root (global idx) or -1
//   areasF[NIMG*HWv]         zeroed at root slots; totals at final roots
//   rootlist[NTILE*LCAP]     packed (area<<12)|inTileIdx
//   rootcnt[NTILE], maxa[16]
//   bitsBG/bitsFG u64[8*4096] keep-verdict bitmasks
//   pf/pbg f32[FBCE], pcf/pcb int[FBCE] per-block CE partials

struct Ctx {
  const float* cams;
  const float* preds;
  int* labels;
  int* areasF;
  int* rootlist;
  int* rootcnt;
  int* maxa;
  unsigned long long* bitsBG;
  unsigned long long* bitsFG;
  float* pf; float* pbg; int* pcf; int* pcb;
  int* bar;
  float* out;
};

// ---------------- union-find (atomicMin only: parents monotone decreasing,
// links point to smaller index => lock-free correct). ----------------
__device__ __forceinline__ int uf_find(int* L, int x) {
  int p = L[x];
  while (p != x) {
    int gp = L[p];
    if (gp != p) atomicMin(&L[x], gp);  // grandparent compression (monotone)
    x = gp;
    p = L[x];
  }
  return x;
}

__device__ __forceinline__ int find_ro(const int* __restrict__ L, int x) {
  int p = L[x];
  while (p != x) { x = p; p = L[x]; }
  return x;
}

__device__ __forceinline__ void uf_union(int* L, int a, int b) {
  a = uf_find(L, a);
  b = uf_find(L, b);
  while (a != b) {
    if (a < b) { int t = a; a = b; b = t; }  // ensure a > b
    int old = atomicMin(&L[a], b);
    if (old == a) return;
    a = old;
  }
}

// Two-level grid barrier: 64 spread arrival lines (NBLK/64 arrivals each) ->
// 1 done line (64 adds) -> release flag. Monotone counters across phases.
// __threadfence() = agent release/acquire for ordinary loads/stores handed
// across the barrier (cross-XCD coherence). BOUNDED spin: if co-residency is
// ever violated, degrade to a wrong answer instead of a GPU hang.
__device__ __forceinline__ void gridbar(int* bar, int ph) {
  __syncthreads();
  if (threadIdx.x == 0) {
    __threadfence();                                     // release data
    int slot = blockIdx.x & 63;
    int v = __hip_atomic_fetch_add(&bar[slot << 5], 1, __ATOMIC_ACQ_REL,
                                   __HIP_MEMORY_SCOPE_AGENT);
    if (v == ph * (NBLK / 64) - 1) {                     // last arrival, slot
      int d = __hip_atomic_fetch_add(&bar[2048], 1, __ATOMIC_ACQ_REL,
                                     __HIP_MEMORY_SCOPE_AGENT);
      if (d == ph * 64 - 1)                              // last slot overall
        __hip_atomic_store(&bar[2080], ph, __ATOMIC_RELEASE,
                           __HIP_MEMORY_SCOPE_AGENT);
    }
    int guard = 0;
    while (__hip_atomic_load(&bar[2080], __ATOMIC_ACQUIRE,
                             __HIP_MEMORY_SCOPE_AGENT) < ph) {
      __builtin_amdgcn_s_sleep(2);
      if (++guard > (1 << 24)) break;                    // hang-proof
    }
    __threadfence();                                     // acquire
  }
  __syncthreads();
}

// ================= phase bodies (shared by coop + fallback paths) =========

// Per-tile CCL in LDS, run-based (R4-verified). One 64x32 tile per call.
__device__ __forceinline__ void ph_local(const Ctx& c, int tileg,
                                         int* P, int* A) {
  __shared__ int lcount;
  const int tid = threadIdx.x, lane = tid & 63;
  const int img = tileg >> 7, tile = tileg & 127;
  const int tS = tile >> 3, tX = tile & 7;
  const int oy = tS * TH, ox = tX * TW;
  const int gbase = img << LOG2HW;
  const int b = img & 7;
  const bool fg = (img & 8) != 0;

  __syncthreads();                     // protect P/A/lcount reuse across calls
  if (tid == 0) lcount = 0;

  // pass 1: mask load + per-row run-start init (wave covers one row)
  #pragma unroll
  for (int it = 0; it < 8; ++it) {
    int i  = it * NTHR + tid;          // i & 63 == lane
    int ly = i >> 6;
    float cv = c.cams[(b << LOG2HW) + ((oy + ly) << 9) + (ox + lane)];
    bool m = fg ? (cv > 0.6f) : (cv >= 0.2f);
    unsigned long long bm = __ballot(m);
    int par = -1;
    if (m) {
      unsigned long long below = (1ULL << lane) - 1ULL;
      unsigned long long z = (~bm) & below;
      int rs = z ? (64 - __clzll(z)) : 0;
      par = (ly << 6) + rs;
    }
    P[i] = par;
    A[i] = 0;
  }
  __syncthreads();

  // pass 2: vertical unions, one per overlap segment (dedup via west pair)
  #pragma unroll
  for (int it = 0; it < 8; ++it) {
    int i = it * NTHR + tid;
    if (i >= TW && P[i] >= 0 && P[i - TW] >= 0) {
      bool skip = (lane > 0) && (P[i - 1] >= 0) && (P[i - TW - 1] >= 0);
      if (!skip) uf_union(P, i, i - TW);
    }
  }
  __syncthreads();

  // pass 3: per-run find + shuffle broadcast + per-run area add
  #pragma unroll
  for (int it = 0; it < 8; ++it) {
    int i = it * NTHR + tid;
    bool m = P[i] >= 0;
    unsigned long long bm = __ballot(m);
    int rs = 0;
    if (m) {
      unsigned long long below = (1ULL << lane) - 1ULL;
      unsigned long long z = (~bm) & below;
      rs = z ? (64 - __clzll(z)) : 0;
    }
    bool isStart = m && (rs == lane);
    int r = -1;
    if (isStart) r = find_ro(P, i);
    int root = __shfl(r, rs);
    if (m) P[i] = root;
    if (isStart) {
      unsigned long long t = (~bm) >> lane;
      int runlen = t ? (__ffsll((long long)t) - 1) : (64 - lane);
      atomicAdd(&A[root], runlen);
    }
  }
  __syncthreads();

  // pass 4: labels write + wave-aggregated root-list append + areasF zero
  int lbase = tileg << 10;             // LCAP entries per tile
  #pragma unroll
  for (int it = 0; it < 8; ++it) {
    int i  = it * NTHR + tid;
    int ly = i >> 6;
    int g  = ((oy + ly) << 9) + (ox + lane);
    int p  = P[i];
    int lab = -1;
    if (p >= 0) lab = ((oy + (p >> 6)) << 9) + (ox + (p & 63));
    c.labels[gbase + g] = lab;
    bool isRoot = (p == i);
    unsigned long long bm = __ballot(isRoot);
    int nr = __popcll(bm);
    int basepos = 0;
    if (lane == 0 && nr) basepos = atomicAdd(&lcount, nr);
    basepos = __shfl(basepos, 0);
    if (isRoot) {
      int off = (int)__popcll(bm & ((1ULL << lane) - 1ULL));
      c.rootlist[lbase + basepos + off] = (A[i] << 12) | i;
      c.areasF[gbase + g] = 0;         // sparse zero (fill poisons ws)
    }
  }
  __syncthreads();
  if (tid == 0) c.rootcnt[tileg] = lcount;
}

// Cross-tile border unions: one work item t in [0, NIMG*22*512).
__device__ __forceinline__ void ph_border(const Ctx& c, int t) {
  const int per_img = 22 * Wdim;       // 7 vertical + 15 horizontal seams
  int im = t / per_img;
  int r  = t - im * per_img;
  int k = r >> 9, j = r & (Wdim - 1);
  int* L = c.labels + (im << LOG2HW);
  if (k < 7) {                         // vertical: x = 64k+63, union east
    int x = TW * k + (TW - 1);
    int p = (j << 9) + x, q = p + 1;
    if (L[p] >= 0 && L[q] >= 0) {
      bool skip = (j > 0) && (L[p - Wdim] >= 0) && (L[q - Wdim] >= 0);
      if (!skip) uf_union(L, p, q);
    }
  } else {                             // horizontal: y = 32h+31, union south
    int y = TH * (k - 7) + (TH - 1);
    int p = (y << 9) + j, q = p + Wdim;
    if (L[p] >= 0 && L[q] >= 0) {
      bool skip = (j > 0) && (L[p - 1] >= 0) && (L[q - 1] >= 0);
      if (!skip) uf_union(L, p, q);
    }
  }
}

// List flatten + area push + running max (last adder observes the total).
__device__ __forceinline__ void ph_flat(const Ctx& c, int tileg) {
  __shared__ int lm[4];
  const int tid = threadIdx.x;
  const int img = tileg >> 7, tile = tileg & 127;
  const int tS = tile >> 3, tX = tile & 7;
  const int oy = tS * TH, ox = tX * TW;
  __syncthreads();                     // protect lm reuse across calls
  int cnt = c.rootcnt[tileg];
  int lbase = tileg << 10;
  int* L  = c.labels + (img << LOG2HW);
  int* AF = c.areasF + (img << LOG2HW);
  int mymax = 0;
  for (int e = tid; e < cnt; e += NTHR) {
    int ent  = c.rootlist[lbase + e];
    int i    = ent & 4095;
    int area = ent >> 12;
    int g = ((oy + (i >> 6)) << 9) + (ox + (i & 63));
    int fr = find_ro(L, g);
    L[g] = fr;                         // own slot -> final root
    int prev = atomicAdd(&AF[fr], area);
    mymax = max(mymax, prev + area);
  }
  #pragma unroll
  for (int off = 32; off > 0; off >>= 1)
    mymax = max(mymax, __shfl_down(mymax, off));
  int wave = tid >> 6;
  if ((tid & 63) == 0) lm[wave] = mymax;
  __syncthreads();
  if (tid == 0) {
    int bm = max(max(lm[0], lm[1]), max(lm[2], lm[3]));
    if (bm > 0) atomicMax(&c.maxa[img], bm);
  }
}

// Verdicts + bit pack for one tile (R4-verified vmerge body).
__device__ __forceinline__ void ph_vmerge(const Ctx& c, int tileg,
                                          unsigned char* V) {
  const int tid = threadIdx.x;
  const int img = tileg >> 7, tile = tileg & 127;
  const int tS = tile >> 3, tX = tile & 7;
  const int oy = tS * TH, ox = tX * TW;
  __syncthreads();                     // protect V reuse across calls
  int cnt = c.rootcnt[tileg];
  int lbase = tileg << 10;
  int mx = c.maxa[img];
  const int* L  = c.labels + (img << LOG2HW);
  const int* AF = c.areasF + (img << LOG2HW);
  for (int e = tid; e < cnt; e += NTHR) {
    int i = c.rootlist[lbase + e] & 4095;
    int g = ((oy + (i >> 6)) << 9) + (ox + (i & 63));
    V[i] = (2 * AF[L[g]] > mx) ? 1 : 0;
  }
  __syncthreads();
  unsigned long long* dst = (img < 8) ? (c.bitsBG + ((img & 7) << 12))
                                      : (c.bitsFG + ((img & 7) << 12));
  #pragma unroll
  for (int it = 0; it < 2; ++it) {
    int grp = it * NTHR + tid;         // 0..511 (4-px groups), 16 per row
    int row = grp >> 4;                // 0..31
    int4 lb = *(const int4*)&L[((oy + row) << 9) + ox + ((grp & 15) << 2)];
    unsigned nib = 0;
    if (lb.x >= 0) nib |= (unsigned)V[(((lb.x >> 9) & 31) << 6) | (lb.x & 63)];
    if (lb.y >= 0) nib |= (unsigned)V[(((lb.y >> 9) & 31) << 6) | (lb.y & 63)] << 1;
    if (lb.z >= 0) nib |= (unsigned)V[(((lb.z >> 9) & 31) << 6) | (lb.z & 63)] << 2;
    if (lb.w >= 0) nib |= (unsigned)V[(((lb.w >> 9) & 31) << 6) | (lb.w & 63)] << 3;
    unsigned long long w = (unsigned long long)nib << ((grp & 15) << 2);
    w |= __shfl_xor(w, 1);
    w |= __shfl_xor(w, 2);
    w |= __shfl_xor(w, 4);
    w |= __shfl_xor(w, 8);
    if ((tid & 15) == 0) dst[((oy + row) << 3) + tX] = w;
  }
}

// Streaming CE over a grid-stride range; block partial -> distinct address.
__device__ __forceinline__ void ph_ce(const Ctx& c, int bid, int g0, int gs) {
  __shared__ float lsf[4], lsb[4];
  __shared__ int   lcf[4], lcb[4];
  float sfg = 0.f, sbg = 0.f;
  int cf = 0, cb = 0;
  for (int g = g0; g < CETOT; g += gs) {
    int g8 = g & 32767;
    int pb = g >> 15;                  // 0..23
    int b = pb & 7, p = pb >> 3;
    int wi = (b << 12) + (g8 >> 3);
    int sh = (g8 & 7) << 3;
    unsigned nB = (unsigned)(c.bitsBG[wi] >> sh) & 255u;
    unsigned nF = (unsigned)(c.bitsFG[wi] >> sh) & 255u;
    const float* pbase = c.preds + ((size_t)((p * Bsz + b) * 2) << LOG2HW);
    int px = g8 << 3;
    float4 A0a = *(const float4*)&pbase[px];
    float4 A0b = *(const float4*)&pbase[px + 4];
    float4 A1a = *(const float4*)&pbase[HWv + px];
    float4 A1b = *(const float4*)&pbase[HWv + px + 4];
    float d[8] = {A0a.x - A1a.x, A0a.y - A1a.y, A0a.z - A1a.z, A0a.w - A1a.w,
                  A0b.x - A1b.x, A0b.y - A1b.y, A0b.z - A1b.z, A0b.w - A1b.w};
    #pragma unroll
    for (int j = 0; j < 8; ++j) {
      float sp = logf(1.f + expf(-fabsf(d[j])));
      bool vfj = (nF >> j) & 1u;
      bool vbj = !((nB >> j) & 1u);
      sfg += vfj ? (fmaxf(d[j], 0.f) + sp) : 0.f;
      sbg += vbj ? (fmaxf(-d[j], 0.f) + sp) : 0.f;
    }
    if (p == 0) {                      // count each pixel ONCE
      cf += __popc(nF);
      cb += 8 - __popc(nB);
    }
  }
  #pragma unroll
  for (int off = 32; off > 0; off >>= 1) {
    sfg += __shfl_down(sfg, off);
    sbg += __shfl_down(sbg, off);
    cf  += __shfl_down(cf, off);
    cb  += __shfl_down(cb, off);
  }
  int wave = threadIdx.x >> 6;
  if ((threadIdx.x & 63) == 0) {
    lsf[wave] = sfg; lsb[wave] = sbg; lcf[wave] = cf; lcb[wave] = cb;
  }
  __syncthreads();
  if (threadIdx.x == 0) {
    c.pf[bid]  = lsf[0] + lsf[1] + lsf[2] + lsf[3];
    c.pbg[bid] = lsb[0] + lsb[1] + lsb[2] + lsb[3];
    c.pcf[bid] = lcf[0] + lcf[1] + lcf[2] + lcf[3];
    c.pcb[bid] = lcb[0] + lcb[1] + lcb[2] + lcb[3];
  }
}

// Final reduce of npart block partials (run by one block).
__device__ __forceinline__ void ph_final(const Ctx& c, int npart) {
  __shared__ double dsf[4], dsb[4];
  __shared__ int    icf[4], icb[4];
  int t = threadIdx.x;
  double sf = 0.0, sb = 0.0;
  int cf = 0, cb = 0;
  for (int k = t; k < npart; k += NTHR) {
    sf += (double)c.pf[k];
    sb += (double)c.pbg[k];
    cf += c.pcf[k];
    cb += c.pcb[k];
  }
  #pragma unroll
  for (int off = 32; off > 0; off >>= 1) {
    sf += __shfl_down(sf, off);
    sb += __shfl_down(sb, off);
    cf += __shfl_down(cf, off);
    cb += __shfl_down(cb, off);
  }
  int wave = t >> 6;
  if ((t & 63) == 0) { dsf[wave] = sf; dsb[wave] = sb; icf[wave] = cf; icb[wave] = cb; }
  __syncthreads();
  if (t == 0) {
    double tf = dsf[0] + dsf[1] + dsf[2] + dsf[3];
    double tb = dsb[0] + dsb[1] + dsb[2] + dsb[3];
    int af_ = icf[0] + icf[1] + icf[2] + icf[3];
    int ab_ = icb[0] + icb[1] + icb[2] + icb[3];
    double df = af_ > 0 ? (double)af_ : 1.0;
    double db = ab_ > 0 ? (double)ab_ : 1.0;
    c.out[0] = (float)(tf / df + tb / db);
  }
}

// ================= cooperative mega-kernel =================
__global__ __launch_bounds__(NTHR, 4) void k_mega(Ctx c) {
  __shared__ int P[TPIX];              // 8 KB
  __shared__ int A[TPIX];              // 8 KB (aliased as V in phase 4)
  const int bid = blockIdx.x;

  if (bid == 0 && threadIdx.x < NIMG) c.maxa[threadIdx.x] = 0;

  ph_local(c, bid, P, A);              // phase 1: 2048 tiles, 2 per block
  ph_local(c, bid + NBLK, P, A);
  gridbar(c.bar, 1);

  {                                    // phase 2: border unions (one pass)
    int t = bid * NTHR + threadIdx.x;
    if (t < NIMG * 22 * Wdim) ph_border(c, t);
  }
  gridbar(c.bar, 2);

  ph_flat(c, bid);                     // phase 3
  ph_flat(c, bid + NBLK);
  gridbar(c.bar, 3);

  ph_vmerge(c, bid, (unsigned char*)A);        // phase 4
  ph_vmerge(c, bid + NBLK, (unsigned char*)A);
  gridbar(c.bar, 4);

  ph_ce(c, bid, bid * NTHR + threadIdx.x, NBLK * NTHR);  // phase 5
  gridbar(c.bar, 5);

  if (bid == 0) ph_final(c, NBLK);     // phase 6
}

// ================= fallback split pipeline (same phase code) =============
__global__ __launch_bounds__(NTHR) void fb_local(Ctx c) {
  __shared__ int P[TPIX];
  __shared__ int A[TPIX];
  if (blockIdx.x == 0 && threadIdx.x < NIMG) c.maxa[threadIdx.x] = 0;
  ph_local(c, blockIdx.x, P, A);
}
__global__ __launch_bounds__(NTHR) void fb_border(Ctx c) {
  int t = blockIdx.x * NTHR + threadIdx.x;
  if (t < NIMG * 22 * Wdim) ph_border(c, t);
}
__global__ __launch_bounds__(NTHR) void fb_flat(Ctx c)   { ph_flat(c, blockIdx.x); }
__global__ __launch_bounds__(NTHR) void fb_vmerge(Ctx c) {
  __shared__ unsigned char V[TPIX];
  ph_vmerge(c, blockIdx.x, V);
}
__global__ __launch_bounds__(NTHR) void fb_ce(Ctx c) {
  ph_ce(c, blockIdx.x, blockIdx.x * NTHR + threadIdx.x, FBCE * NTHR);
}
__global__ __launch_bounds__(NTHR) void fb_final(Ctx c)  { ph_final(c, FBCE); }

extern "C" void kernel_launch(void* const* d_in, const int* in_sizes, int n_in,
                              void* d_out, int out_size, void* d_ws, size_t ws_size,
                              hipStream_t stream) {
  (void)in_sizes; (void)n_in; (void)out_size; (void)ws_size;
  Ctx c;
  c.cams  = (const float*)d_in[1];     // [8,1,512,512]  f32
  c.preds = (const float*)d_in[0];     // [3,8,2,512,512] f32
  c.out   = (float*)d_out;             // scalar f32

  c.bar      = (int*)d_ws;             // 4096 ints, memset 0 below
  c.labels   = c.bar + 4096;
  c.areasF   = c.labels + NIMG * HWv;
  c.rootlist = c.areasF + NIMG * HWv;  // NTILE*LCAP = 2M ints
  c.rootcnt  = c.rootlist + NTILE * LCAP;
  c.maxa     = c.rootcnt + NTILE;
  c.bitsBG   = (unsigned long long*)(c.maxa + 16);
  c.bitsFG   = c.bitsBG + Bsz * (HWv / 64);
  c.pf  = (float*)(c.bitsFG + Bsz * (HWv / 64));
  c.pbg = c.pf + FBCE;
  c.pcf = (int*)(c.pbg + FBCE);
  c.pcb = c.pcf + FBCE;

  hipMemsetAsync(c.bar, 0, 4096 * sizeof(int), stream);

  void* kargs[] = {&c};
  hipError_t e = hipLaunchCooperativeKernel(reinterpret_cast<void*>(k_mega),
                                            dim3(NBLK), dim3(NTHR), kargs, 0,
                                            stream);
  if (e != hipSuccess) {               // fallback: verified split pipeline
    (void)hipGetLastError();           // clear sticky error
    fb_local <<<NTILE, NTHR, 0, stream>>>(c);
    fb_border<<<(NIMG * 22 * Wdim + NTHR - 1) / NTHR, NTHR, 0, stream>>>(c);
    fb_flat  <<<NTILE, NTHR, 0, stream>>>(c);
    fb_vmerge<<<NTILE, NTHR, 0, stream>>>(c);
    fb_ce    <<<FBCE, NTHR, 0, stream>>>(c);
    fb_final <<<1, NTHR, 0, stream>>>(c);
  }
}

// Round 7
// 303.150 us; speedup vs baseline: 2.7107x; 2.7107x over previous
//
#include <hip/hip_runtime.h>
#include <hip/hip_bf16.h>
#include <math.h>

// Problem constants (reference: B=8, H=W=512)
#define Bsz    8
#define Wdim   512
#define HWv    (512 * 512)       // 262144 = 2^18
#define LOG2HW 18
#define NIMG   16                // {bg(0..7), fg(8..15)}
#define TILE   64                // 64x64 tiles -> 8x8 = 64 tiles per image
#define TPIX   (TILE * TILE)     // 4096
#define CEBLK  6144              // k_ce blocks: 3 preds * 8 b * 256 blocks
#define CNTBLK 2048              // k_ce blocks with p==0 (count producers)

// ws layout (int32 units):
//   [0, NIMG*HWv)            labels: pixel -> tile root (global idx) or -1;
//                            tile-root slots -> final root after k_flatten
//   [NIMG*HWv, 2*NIMG*HWv)   areas: tile roots hold partials; final roots
//                            hold totals after k_flatten; 0 elsewhere
//   [2*NIMG*HWv, +16)        per-image max area
//   then (8-byte aligned):   double sums[2]; int counts[2] (legacy pad)
//   then: u64 bitsBG[8*4096]; u64 bitsFG[8*4096]   (keep-verdict bitmasks)
//   then: float pf[CEBLK]; float pbg[CEBLK]; int pcf[CNTBLK]; int pcb[CNTBLK]
//   then: int cedone[1]  (zeroed by k_border block 0)

// ---------------- union-find (atomicMin only: parents monotone decreasing,
// links point to smaller index => lock-free correct). ----------------
__device__ __forceinline__ int uf_find(int* L, int x) {
  int p = L[x];
  while (p != x) {
    int gp = L[p];
    if (gp != p) atomicMin(&L[x], gp);  // grandparent compression (monotone)
    x = gp;
    p = L[x];
  }
  return x;
}

// Read-only find: no compression writes.
__device__ __forceinline__ int find_ro(const int* __restrict__ L, int x) {
  int p = L[x];
  while (p != x) { x = p; p = L[x]; }
  return x;
}

__device__ __forceinline__ void uf_union(int* L, int a, int b) {
  a = uf_find(L, a);
  b = uf_find(L, b);
  while (a != b) {
    if (a < b) { int t = a; a = b; b = t; }  // ensure a > b
    int old = atomicMin(&L[a], b);
    if (old == a) return;  // linked a -> b
    a = old;               // parent already lowered; keep merging
  }
}

// ---------------- kernels ----------------

// Per-tile CCL in LDS, run-based: a wave == one 64-px row. Pixels link
// directly to their run start (ballot, no atomics); vertical unions only at
// the leftmost pixel of each overlap segment. Finds are PER-RUN (run-start
// lanes only); other lanes take the root via shuffle. Labels are written
// straight from the in-register root in pass 3 (no P write-back); pass 4 is
// an areas-only writeout using the invariant P[i]==i <=> root.
__global__ __launch_bounds__(1024) void k_local(const float* __restrict__ cams,
                                                int* __restrict__ labels,
                                                int* __restrict__ areas) {
  int img  = blockIdx.x >> 6;          // 0..15
  int tile = blockIdx.x & 63;          // 8x8 tiles
  int tY = tile >> 3, tX = tile & 7;
  int b = img & 7;
  bool fg = (img & 8) != 0;
  int gbase = img << LOG2HW;
  int oy = tY * TILE, ox = tX * TILE;
  int lane = threadIdx.x & 63;

  __shared__ int P[TPIX];              // parents, 16 KB
  __shared__ int A[TPIX];              // local areas, 16 KB

  // pass 1: mask load + per-row run-start init (wave covers exactly one row)
  #pragma unroll
  for (int it = 0; it < 4; ++it) {
    int i  = it * 1024 + threadIdx.x;  // i & 63 == lane
    int ly = i >> 6;
    float c = cams[(b << LOG2HW) + ((oy + ly) << 9) + (ox + lane)];
    bool m = fg ? (c > 0.6f) : (c >= 0.2f);
    unsigned long long bm = __ballot(m);
    int par = -1;
    if (m) {
      unsigned long long below = (1ULL << lane) - 1ULL;
      unsigned long long z = (~bm) & below;       // zeros below this lane
      int rs = z ? (64 - __clzll(z)) : 0;          // run start = highest zero + 1
      par = (ly << 6) + rs;
    }
    P[i] = par;
    A[i] = 0;
  }
  __syncthreads();

  // pass 2: vertical unions, one per overlap segment (dedup via west pair)
  #pragma unroll
  for (int it = 0; it < 4; ++it) {
    int i = it * 1024 + threadIdx.x;
    if (i >= TILE && P[i] >= 0 && P[i - TILE] >= 0) {
      bool skip = (lane > 0) && (P[i - 1] >= 0) && (P[i - TILE - 1] >= 0);
      if (!skip) uf_union(P, i, i - TILE);
    }
  }
  __syncthreads();

  // pass 3: PER-RUN find + shuffle broadcast + per-run area add + DIRECT
  // label write (root already in-register; no P write-back needed).
  #pragma unroll
  for (int it = 0; it < 4; ++it) {
    int i = it * 1024 + threadIdx.x;
    int ly = i >> 6;
    bool m = P[i] >= 0;
    unsigned long long bm = __ballot(m);
    int rs = 0;
    if (m) {
      unsigned long long below = (1ULL << lane) - 1ULL;
      unsigned long long z = (~bm) & below;
      rs = z ? (64 - __clzll(z)) : 0;
    }
    bool isStart = m && (rs == lane);
    int r = -1;
    if (isStart) r = find_ro(P, i);
    int root = __shfl(r, rs);          // valid wherever m
    int g = ((oy + ly) << 9) + (ox + lane);
    int lab = -1;
    if (m) lab = ((oy + (root >> 6)) << 9) + (ox + (root & 63));
    labels[gbase + g] = lab;
    if (isStart) {
      unsigned long long t = (~bm) >> lane;
      int runlen = t ? (__ffsll((long long)t) - 1) : (64 - lane);
      atomicAdd(&A[root], runlen);
    }
  }
  __syncthreads();

  // pass 4: areas-only writeout (P[i]==i <=> tile root; A final after barrier)
  #pragma unroll
  for (int it = 0; it < 4; ++it) {
    int i  = it * 1024 + threadIdx.x;
    int ly = i >> 6;
    int g  = ((oy + ly) << 9) + (ox + lane);
    areas[gbase + g] = (P[i] == i) ? A[i] : 0;
  }
}

// Merge across tile boundaries, one union per contiguous overlap segment.
// Also folds the tiny init (maxa + ce done-counter) into block 0.
__global__ void k_border(int* __restrict__ labels, int* __restrict__ maxa,
                         int* __restrict__ cedone) {
  if (blockIdx.x == 0) {
    if (threadIdx.x < NIMG) maxa[threadIdx.x] = 0;
    if (threadIdx.x == 0) cedone[0] = 0;
  }
  const int per_img = 14 * Wdim;       // 7168
  int t = blockIdx.x * blockDim.x + threadIdx.x;
  if (t >= NIMG * per_img) return;
  int img = t / per_img;
  int r   = t - img * per_img;
  int k = r >> 9, j = r & (Wdim - 1);
  int* L = labels + (img << LOG2HW);
  // mask-ness (>=0 vs -1) of label slots is immutable here => dedup stable.
  if (k < 7) {                          // vertical border: x = 64k+63, union east
    int x = TILE * k + (TILE - 1);
    int p = (j << 9) + x, q = p + 1;    // j = y
    if (L[p] >= 0 && L[q] >= 0) {
      bool skip = (j > 0) && (L[p - Wdim] >= 0) && (L[q - Wdim] >= 0);
      if (!skip) uf_union(L, p, q);
    }
  } else {                              // horizontal border: y = 64(k-7)+63, union south
    int y = TILE * (k - 7) + (TILE - 1);
    int p = (y << 9) + j, q = p + Wdim; // j = x
    if (L[p] >= 0 && L[q] >= 0) {
      bool skip = (j > 0) && (L[p - 1] >= 0) && (L[q - 1] >= 0);
      if (!skip) uf_union(L, p, q);
    }
  }
}

// PUSH-ONLY flatten: only tile-root slots (area>0, ~4% of slots) do work:
// find final root, rewrite OWN label slot to it, push partial area with a
// NON-RETURNING atomic. Pixel labels untouched. Stale partials at non-final
// roots are <= component totals, so k_max is unaffected.
__global__ void k_flatten(int* __restrict__ labels, int* __restrict__ areas) {
  int t = blockIdx.x * blockDim.x + threadIdx.x;
  int idx0 = t << 2;
  int4 ar = *(const int4*)&areas[idx0];
  if ((ar.x | ar.y | ar.z | ar.w) <= 0) return;   // all >= 0
  int img  = idx0 >> LOG2HW;
  int base = img << LOG2HW;
  int* L = labels + base;
  int self0 = idx0 - base;
  int4 lab = *(const int4*)&labels[idx0];
  if (ar.x > 0) { int r = find_ro(L, lab.x); L[self0]     = r; if (r != self0)     atomicAdd(&areas[base + r], ar.x); }
  if (ar.y > 0) { int r = find_ro(L, lab.y); L[self0 + 1] = r; if (r != self0 + 1) atomicAdd(&areas[base + r], ar.y); }
  if (ar.z > 0) { int r = find_ro(L, lab.z); L[self0 + 2] = r; if (r != self0 + 2) atomicAdd(&areas[base + r], ar.z); }
  if (ar.w > 0) { int r = find_ro(L, lab.w); L[self0 + 3] = r; if (r != self0 + 3) atomicAdd(&areas[base + r], ar.w); }
}

// Per-image max area: 16 blocks/image, 16 int4 grid-stride reads per thread,
// 1 atomicMax per block.
__global__ void k_max(const int* __restrict__ areas, int* __restrict__ maxa) {
  int img = blockIdx.x >> 4;           // 16 blocks per image
  int seg = blockIdx.x & 15;
  const int4* a4 = (const int4*)(areas + (img << LOG2HW));
  int base = seg * (HWv / 4 / 16);     // 4096 int4 per block
  int m = 0;
  #pragma unroll
  for (int k = 0; k < 16; ++k) {
    int4 v = a4[base + k * 256 + threadIdx.x];
    m = max(m, max(max(v.x, v.y), max(v.z, v.w)));
  }
  #pragma unroll
  for (int off = 32; off > 0; off >>= 1)
    m = max(m, __shfl_down(m, off));
  __shared__ int lm[4];
  int wave = threadIdx.x >> 6;
  if ((threadIdx.x & 63) == 0) lm[wave] = m;
  __syncthreads();
  if (threadIdx.x == 0) {
    int bm = max(max(lm[0], lm[1]), max(lm[2], lm[3]));
    if (bm > 0) atomicMax(&maxa[img], bm);
  }
}

// Materialize per-pixel keep-verdicts as bitmasks (1 bit/px). One gather per
// ROOT slot builds an LDS verdict table; per-pixel resolution is an LDS
// read; bits packed per 64-px row via shfl_xor-OR, one u64 word per row.
__global__ __launch_bounds__(1024) void k_verdict(const int* __restrict__ labels,
                                                  const int* __restrict__ areas,
                                                  const int* __restrict__ maxa,
                                                  unsigned long long* __restrict__ bitsBG,
                                                  unsigned long long* __restrict__ bitsFG) {
  int img  = blockIdx.x >> 6;          // 0..15
  int tile = blockIdx.x & 63;
  int tY = tile >> 3, tX = tile & 7;
  int oy = tY * TILE, ox = tX * TILE;
  int base = img << LOG2HW;
  int mx = maxa[img];

  __shared__ int V[TPIX];              // verdict table (root slots only), 16 KB

  int i  = threadIdx.x << 2;           // in-tile index of 4-px group
  int ly = i >> 6, lx = i & 63;
  int g  = ((oy + ly) << 9) + (ox + lx);    // in-image index
  int4 lb = *(const int4*)&labels[base + g];
  int4 ar = *(const int4*)&areas[base + g];
  // root slots: their label already holds the FINAL root (k_flatten).
  if (ar.x > 0) { V[i + 0] = (2 * areas[base + lb.x] > mx); lb.x = g + 0; }
  if (ar.y > 0) { V[i + 1] = (2 * areas[base + lb.y] > mx); lb.y = g + 1; }
  if (ar.z > 0) { V[i + 2] = (2 * areas[base + lb.z] > mx); lb.z = g + 2; }
  if (ar.w > 0) { V[i + 3] = (2 * areas[base + lb.w] > mx); lb.w = g + 3; }
  __syncthreads();

  // per-pixel verdict nibble (bit j = pixel g+j kept)
  int l[4] = {lb.x, lb.y, lb.z, lb.w};
  unsigned nib = 0;
  #pragma unroll
  for (int j = 0; j < 4; ++j) {
    if (l[j] >= 0) {
      int loc = (((l[j] >> 9) & 63) << 6) | (l[j] & 63);
      nib |= (V[loc] ? 1u : 0u) << j;
    }
  }

  // pack: 16 lanes (lane&15) cover one 64-px row -> one u64 word.
  int lane = threadIdx.x & 63;
  unsigned long long w = (unsigned long long)nib << ((lane & 15) << 2);
  w |= __shfl_xor(w, 1);
  w |= __shfl_xor(w, 2);
  w |= __shfl_xor(w, 4);
  w |= __shfl_xor(w, 8);
  if ((lane & 15) == 0) {
    int wordIdx = ((oy + ly) << 3) + tX;    // (row*512 + ox) / 64
    unsigned long long* dst = (img < 8) ? (bitsBG + ((img & 7) << 12))
                                        : (bitsFG + ((img & 7) << 12));
    dst[wordIdx] = w;
  }
}

// Pure-streaming CE, one thread per (p, b, float4-group): exactly 2 float4
// loads + 2 cached u64 bit-word loads per thread (all issued up front, tiny
// register footprint -> no serialized load chains), 6144 blocks for full TLP.
// Per-block partials to DISTINCT addresses; counts only from p==0 blocks.
// The LAST block (threadfence reduction) folds the final combine in-kernel.
__global__ __launch_bounds__(256) void k_ce(const float* __restrict__ preds,
                                            const unsigned long long* __restrict__ bitsBG,
                                            const unsigned long long* __restrict__ bitsFG,
                                            float* __restrict__ pf,
                                            float* __restrict__ pbg,
                                            int* __restrict__ pcf,
                                            int* __restrict__ pcb,
                                            int* __restrict__ cedone,
                                            float* __restrict__ out) {
  int tid = blockIdx.x * 256 + threadIdx.x;   // [0, 3*8*65536)
  int g4  = tid & 65535;                      // float4 group within image
  int pb  = tid >> 16;                        // 0..23
  int b   = pb & 7;
  int p   = pb >> 3;                          // 0..2 (uniform per block)

  int wi = (b << 12) + (g4 >> 4);             // u64 word index
  int sh = (g4 & 15) << 2;                    // nibble shift within word
  unsigned nB = (unsigned)(bitsBG[wi] >> sh) & 15u;
  unsigned nF = (unsigned)(bitsFG[wi] >> sh) & 15u;

  const float* pbase = preds + ((size_t)((p * Bsz + b) * 2) << LOG2HW);
  int px = g4 << 2;
  float4 A0 = *(const float4*)&pbase[px];
  float4 A1 = *(const float4*)&pbase[HWv + px];

  float d[4] = {A0.x - A1.x, A0.y - A1.y, A0.z - A1.z, A0.w - A1.w};
  float sfg = 0.f, sbg = 0.f;
  #pragma unroll
  for (int j = 0; j < 4; ++j) {
    float sp = logf(1.f + expf(-fabsf(d[j])));
    bool vfj = (nF >> j) & 1u;
    bool vbj = !((nB >> j) & 1u);
    sfg += vfj ? (fmaxf(d[j], 0.f) + sp) : 0.f;
    sbg += vbj ? (fmaxf(-d[j], 0.f) + sp) : 0.f;
  }
  int cf = __popc(nF);
  int cb = 4 - __popc(nB);

  // block reduction: wave64 shuffle -> LDS -> one partial-write per block
  #pragma unroll
  for (int off = 32; off > 0; off >>= 1) {
    sfg += __shfl_down(sfg, off);
    sbg += __shfl_down(sbg, off);
    cf  += __shfl_down(cf, off);
    cb  += __shfl_down(cb, off);
  }
  __shared__ float lsf[4], lsb[4];
  __shared__ int   lcf[4], lcb[4];
  __shared__ int   amLast;
  int wave = threadIdx.x >> 6;
  if ((threadIdx.x & 63) == 0) {
    lsf[wave] = sfg; lsb[wave] = sbg; lcf[wave] = cf; lcb[wave] = cb;
  }
  __syncthreads();
  if (threadIdx.x == 0) {
    pf[blockIdx.x]  = lsf[0] + lsf[1] + lsf[2] + lsf[3];
    pbg[blockIdx.x] = lsb[0] + lsb[1] + lsb[2] + lsb[3];
    if (p == 0) {                       // count each pixel ONCE (p==0 blocks)
      pcf[blockIdx.x] = lcf[0] + lcf[1] + lcf[2] + lcf[3];
      pcb[blockIdx.x] = lcb[0] + lcb[1] + lcb[2] + lcb[3];
    }
    __threadfence();                    // release partials (agent scope)
    int v = atomicAdd(cedone, 1);
    amLast = (v == CEBLK - 1);
  }
  __syncthreads();

  if (amLast) {                         // last block: final combine
    __threadfence();                    // acquire all partials
    int t = threadIdx.x;
    double sf = 0.0, sb = 0.0;
    int acf = 0, acb = 0;
    #pragma unroll
    for (int k = 0; k < CEBLK / 256; ++k) {
      sf += (double)pf[k * 256 + t];
      sb += (double)pbg[k * 256 + t];
    }
    #pragma unroll
    for (int k = 0; k < CNTBLK / 256; ++k) {
      acf += pcf[k * 256 + t];
      acb += pcb[k * 256 + t];
    }
    #pragma unroll
    for (int off = 32; off > 0; off >>= 1) {
      sf  += __shfl_down(sf, off);
      sb  += __shfl_down(sb, off);
      acf += __shfl_down(acf, off);
      acb += __shfl_down(acb, off);
    }
    __shared__ double dsf[4], dsb[4];
    __shared__ int    icf[4], icb[4];
    if ((t & 63) == 0) { dsf[wave] = sf; dsb[wave] = sb; icf[wave] = acf; icb[wave] = acb; }
    __syncthreads();
    if (t == 0) {
      double tf = dsf[0] + dsf[1] + dsf[2] + dsf[3];
      double tb = dsb[0] + dsb[1] + dsb[2] + dsb[3];
      int af_ = icf[0] + icf[1] + icf[2] + icf[3];
      int ab_ = icb[0] + icb[1] + icb[2] + icb[3];
      double df = af_ > 0 ? (double)af_ : 1.0;
      double db = ab_ > 0 ? (double)ab_ : 1.0;
      out[0] = (float)(tf / df + tb / db);
    }
  }
}

extern "C" void kernel_launch(void* const* d_in, const int* in_sizes, int n_in,
                              void* d_out, int out_size, void* d_ws, size_t ws_size,
                              hipStream_t stream) {
  (void)in_sizes; (void)n_in; (void)out_size; (void)ws_size;
  const float* preds = (const float*)d_in[0];  // [3,8,2,512,512] f32
  const float* cams  = (const float*)d_in[1];  // [8,1,512,512]  f32
  float* out = (float*)d_out;                  // scalar f32

  int* labels = (int*)d_ws;
  int* areas  = labels + NIMG * HWv;
  int* maxa   = areas + NIMG * HWv;
  double* sums = (double*)(maxa + 16);         // legacy slot (keeps alignment)
  int* counts  = (int*)(sums + 2);
  unsigned long long* bitsBG = (unsigned long long*)(counts + 2);  // 8-aligned
  unsigned long long* bitsFG = bitsBG + Bsz * (HWv / 64);          // 256 KB each
  float* pf  = (float*)(bitsFG + Bsz * (HWv / 64));
  float* pbg = pf + CEBLK;
  int*   pcf = (int*)(pbg + CEBLK);
  int*   pcb = pcf + CNTBLK;
  int*   cedone = pcb + CNTBLK;

  const int threads = 256;

  k_local  <<<NIMG * 64, 1024, 0, stream>>>(cams, labels, areas);
  k_border <<<(NIMG * 14 * Wdim + threads - 1) / threads, threads, 0, stream>>>(labels, maxa, cedone);
  k_flatten<<<NIMG * HWv / (threads * 4), threads, 0, stream>>>(labels, areas);
  k_max    <<<NIMG * 16, threads, 0, stream>>>(areas, maxa);
  k_verdict<<<NIMG * 64, 1024, 0, stream>>>(labels, areas, maxa, bitsBG, bitsFG);
  k_ce     <<<CEBLK, threads, 0, stream>>>(preds, bitsBG, bitsFG, pf, pbg, pcf, pcb, cedone, out);
}

// Round 8
// 156.299 us; speedup vs baseline: 5.2576x; 1.9396x over previous
//
#include <hip/hip_runtime.h>
#include <hip/hip_bf16.h>
#include <math.h>

// Problem constants (reference: B=8, H=W=512)
#define Bsz    8
#define Wdim   512
#define HWv    (512 * 512)       // 262144 = 2^18
#define LOG2HW 18
#define NIMG   16                // {bg(0..7), fg(8..15)}
#define TILE   64                // 64x64 tiles -> 8x8 = 64 tiles per image
#define TPIX   (TILE * TILE)     // 4096
#define CEBLK  6144              // k_ce blocks: 3 preds * 8 b * 256 blocks
#define CNTBLK 2048              // k_ce blocks with p==0 (count producers)

// ws layout (int32 units):
//   [0, NIMG*HWv)            labels: pixel -> tile root (global idx) or -1;
//                            tile-root slots -> final root after k_flatten
//   [NIMG*HWv, 2*NIMG*HWv)   areas: tile roots hold partials; final roots
//                            hold totals after k_flatten; 0 elsewhere
//   [2*NIMG*HWv, +16)        per-image max area
//   then (8-byte aligned):   double sums[2]; int counts[2] (legacy pad)
//   then: u64 bitsBG[8*4096]; u64 bitsFG[8*4096]   (keep-verdict bitmasks)
//   then: float pf[CEBLK]; float pbg[CEBLK]; int pcf[CNTBLK]; int pcb[CNTBLK]

// ---------------- union-find (atomicMin only: parents monotone decreasing,
// links point to smaller index => lock-free correct). ----------------
__device__ __forceinline__ int uf_find(int* L, int x) {
  int p = L[x];
  while (p != x) {
    int gp = L[p];
    if (gp != p) atomicMin(&L[x], gp);  // grandparent compression (monotone)
    x = gp;
    p = L[x];
  }
  return x;
}

// Read-only find: no compression writes.
__device__ __forceinline__ int find_ro(const int* __restrict__ L, int x) {
  int p = L[x];
  while (p != x) { x = p; p = L[x]; }
  return x;
}

__device__ __forceinline__ void uf_union(int* L, int a, int b) {
  a = uf_find(L, a);
  b = uf_find(L, b);
  while (a != b) {
    if (a < b) { int t = a; a = b; b = t; }  // ensure a > b
    int old = atomicMin(&L[a], b);
    if (old == a) return;  // linked a -> b
    a = old;               // parent already lowered; keep merging
  }
}

// ---------------- kernels ----------------

// Per-tile CCL in LDS, run-based: a wave == one 64-px row. Pixels link
// directly to their run start (ballot, no atomics); vertical unions only at
// the leftmost pixel of each overlap segment. Finds are PER-RUN (run-start
// lanes only); other lanes take the root via shuffle. Labels are written
// straight from the in-register root in pass 3 (no P write-back); pass 4 is
// an areas-only writeout using the invariant P[i]==i <=> root.
__global__ __launch_bounds__(1024) void k_local(const float* __restrict__ cams,
                                                int* __restrict__ labels,
                                                int* __restrict__ areas) {
  int img  = blockIdx.x >> 6;          // 0..15
  int tile = blockIdx.x & 63;          // 8x8 tiles
  int tY = tile >> 3, tX = tile & 7;
  int b = img & 7;
  bool fg = (img & 8) != 0;
  int gbase = img << LOG2HW;
  int oy = tY * TILE, ox = tX * TILE;
  int lane = threadIdx.x & 63;

  __shared__ int P[TPIX];              // parents, 16 KB
  __shared__ int A[TPIX];              // local areas, 16 KB

  // pass 1: mask load + per-row run-start init (wave covers exactly one row)
  #pragma unroll
  for (int it = 0; it < 4; ++it) {
    int i  = it * 1024 + threadIdx.x;  // i & 63 == lane
    int ly = i >> 6;
    float c = cams[(b << LOG2HW) + ((oy + ly) << 9) + (ox + lane)];
    bool m = fg ? (c > 0.6f) : (c >= 0.2f);
    unsigned long long bm = __ballot(m);
    int par = -1;
    if (m) {
      unsigned long long below = (1ULL << lane) - 1ULL;
      unsigned long long z = (~bm) & below;       // zeros below this lane
      int rs = z ? (64 - __clzll(z)) : 0;          // run start = highest zero + 1
      par = (ly << 6) + rs;
    }
    P[i] = par;
    A[i] = 0;
  }
  __syncthreads();

  // pass 2: vertical unions, one per overlap segment (dedup via west pair)
  #pragma unroll
  for (int it = 0; it < 4; ++it) {
    int i = it * 1024 + threadIdx.x;
    if (i >= TILE && P[i] >= 0 && P[i - TILE] >= 0) {
      bool skip = (lane > 0) && (P[i - 1] >= 0) && (P[i - TILE - 1] >= 0);
      if (!skip) uf_union(P, i, i - TILE);
    }
  }
  __syncthreads();

  // pass 3: PER-RUN find + shuffle broadcast + per-run area add + DIRECT
  // label write (root already in-register; no P write-back needed).
  #pragma unroll
  for (int it = 0; it < 4; ++it) {
    int i = it * 1024 + threadIdx.x;
    int ly = i >> 6;
    bool m = P[i] >= 0;
    unsigned long long bm = __ballot(m);
    int rs = 0;
    if (m) {
      unsigned long long below = (1ULL << lane) - 1ULL;
      unsigned long long z = (~bm) & below;
      rs = z ? (64 - __clzll(z)) : 0;
    }
    bool isStart = m && (rs == lane);
    int r = -1;
    if (isStart) r = find_ro(P, i);
    int root = __shfl(r, rs);          // valid wherever m
    int g = ((oy + ly) << 9) + (ox + lane);
    int lab = -1;
    if (m) lab = ((oy + (root >> 6)) << 9) + (ox + (root & 63));
    labels[gbase + g] = lab;
    if (isStart) {
      unsigned long long t = (~bm) >> lane;
      int runlen = t ? (__ffsll((long long)t) - 1) : (64 - lane);
      atomicAdd(&A[root], runlen);
    }
  }
  __syncthreads();

  // pass 4: areas-only writeout (P[i]==i <=> tile root; A final after barrier)
  #pragma unroll
  for (int it = 0; it < 4; ++it) {
    int i  = it * 1024 + threadIdx.x;
    int ly = i >> 6;
    int g  = ((oy + ly) << 9) + (ox + lane);
    areas[gbase + g] = (P[i] == i) ? A[i] : 0;
  }
}

// Merge across tile boundaries, one union per contiguous overlap segment.
// Also folds the tiny init (maxa) into block 0.
__global__ void k_border(int* __restrict__ labels, int* __restrict__ maxa) {
  if (blockIdx.x == 0) {
    if (threadIdx.x < NIMG) maxa[threadIdx.x] = 0;
  }
  const int per_img = 14 * Wdim;       // 7168
  int t = blockIdx.x * blockDim.x + threadIdx.x;
  if (t >= NIMG * per_img) return;
  int img = t / per_img;
  int r   = t - img * per_img;
  int k = r >> 9, j = r & (Wdim - 1);
  int* L = labels + (img << LOG2HW);
  // mask-ness (>=0 vs -1) of label slots is immutable here => dedup stable.
  if (k < 7) {                          // vertical border: x = 64k+63, union east
    int x = TILE * k + (TILE - 1);
    int p = (j << 9) + x, q = p + 1;    // j = y
    if (L[p] >= 0 && L[q] >= 0) {
      bool skip = (j > 0) && (L[p - Wdim] >= 0) && (L[q - Wdim] >= 0);
      if (!skip) uf_union(L, p, q);
    }
  } else {                              // horizontal border: y = 64(k-7)+63, union south
    int y = TILE * (k - 7) + (TILE - 1);
    int p = (y << 9) + j, q = p + Wdim; // j = x
    if (L[p] >= 0 && L[q] >= 0) {
      bool skip = (j > 0) && (L[p - 1] >= 0) && (L[q - 1] >= 0);
      if (!skip) uf_union(L, p, q);
    }
  }
}

// PUSH-ONLY flatten: only tile-root slots (area>0, ~4% of slots) do work:
// find final root, rewrite OWN label slot to it, push partial area with a
// NON-RETURNING atomic. Pixel labels untouched. Stale partials at non-final
// roots are <= component totals, so k_max is unaffected.
__global__ void k_flatten(int* __restrict__ labels, int* __restrict__ areas) {
  int t = blockIdx.x * blockDim.x + threadIdx.x;
  int idx0 = t << 2;
  int4 ar = *(const int4*)&areas[idx0];
  if ((ar.x | ar.y | ar.z | ar.w) <= 0) return;   // all >= 0
  int img  = idx0 >> LOG2HW;
  int base = img << LOG2HW;
  int* L = labels + base;
  int self0 = idx0 - base;
  int4 lab = *(const int4*)&labels[idx0];
  if (ar.x > 0) { int r = find_ro(L, lab.x); L[self0]     = r; if (r != self0)     atomicAdd(&areas[base + r], ar.x); }
  if (ar.y > 0) { int r = find_ro(L, lab.y); L[self0 + 1] = r; if (r != self0 + 1) atomicAdd(&areas[base + r], ar.y); }
  if (ar.z > 0) { int r = find_ro(L, lab.z); L[self0 + 2] = r; if (r != self0 + 2) atomicAdd(&areas[base + r], ar.z); }
  if (ar.w > 0) { int r = find_ro(L, lab.w); L[self0 + 3] = r; if (r != self0 + 3) atomicAdd(&areas[base + r], ar.w); }
}

// Per-image max area: 16 blocks/image, 16 int4 grid-stride reads per thread,
// 1 atomicMax per block.
__global__ void k_max(const int* __restrict__ areas, int* __restrict__ maxa) {
  int img = blockIdx.x >> 4;           // 16 blocks per image
  int seg = blockIdx.x & 15;
  const int4* a4 = (const int4*)(areas + (img << LOG2HW));
  int base = seg * (HWv / 4 / 16);     // 4096 int4 per block
  int m = 0;
  #pragma unroll
  for (int k = 0; k < 16; ++k) {
    int4 v = a4[base + k * 256 + threadIdx.x];
    m = max(m, max(max(v.x, v.y), max(v.z, v.w)));
  }
  #pragma unroll
  for (int off = 32; off > 0; off >>= 1)
    m = max(m, __shfl_down(m, off));
  __shared__ int lm[4];
  int wave = threadIdx.x >> 6;
  if ((threadIdx.x & 63) == 0) lm[wave] = m;
  __syncthreads();
  if (threadIdx.x == 0) {
    int bm = max(max(lm[0], lm[1]), max(lm[2], lm[3]));
    if (bm > 0) atomicMax(&maxa[img], bm);
  }
}

// Materialize per-pixel keep-verdicts as bitmasks (1 bit/px). One gather per
// ROOT slot builds an LDS verdict table; per-pixel resolution is an LDS
// read; bits packed per 64-px row via shfl_xor-OR, one u64 word per row.
__global__ __launch_bounds__(1024) void k_verdict(const int* __restrict__ labels,
                                                  const int* __restrict__ areas,
                                                  const int* __restrict__ maxa,
                                                  unsigned long long* __restrict__ bitsBG,
                                                  unsigned long long* __restrict__ bitsFG) {
  int img  = blockIdx.x >> 6;          // 0..15
  int tile = blockIdx.x & 63;
  int tY = tile >> 3, tX = tile & 7;
  int oy = tY * TILE, ox = tX * TILE;
  int base = img << LOG2HW;
  int mx = maxa[img];

  __shared__ int V[TPIX];              // verdict table (root slots only), 16 KB

  int i  = threadIdx.x << 2;           // in-tile index of 4-px group
  int ly = i >> 6, lx = i & 63;
  int g  = ((oy + ly) << 9) + (ox + lx);    // in-image index
  int4 lb = *(const int4*)&labels[base + g];
  int4 ar = *(const int4*)&areas[base + g];
  // root slots: their label already holds the FINAL root (k_flatten).
  if (ar.x > 0) { V[i + 0] = (2 * areas[base + lb.x] > mx); lb.x = g + 0; }
  if (ar.y > 0) { V[i + 1] = (2 * areas[base + lb.y] > mx); lb.y = g + 1; }
  if (ar.z > 0) { V[i + 2] = (2 * areas[base + lb.z] > mx); lb.z = g + 2; }
  if (ar.w > 0) { V[i + 3] = (2 * areas[base + lb.w] > mx); lb.w = g + 3; }
  __syncthreads();

  // per-pixel verdict nibble (bit j = pixel g+j kept)
  int l[4] = {lb.x, lb.y, lb.z, lb.w};
  unsigned nib = 0;
  #pragma unroll
  for (int j = 0; j < 4; ++j) {
    if (l[j] >= 0) {
      int loc = (((l[j] >> 9) & 63) << 6) | (l[j] & 63);
      nib |= (V[loc] ? 1u : 0u) << j;
    }
  }

  // pack: 16 lanes (lane&15) cover one 64-px row -> one u64 word.
  int lane = threadIdx.x & 63;
  unsigned long long w = (unsigned long long)nib << ((lane & 15) << 2);
  w |= __shfl_xor(w, 1);
  w |= __shfl_xor(w, 2);
  w |= __shfl_xor(w, 4);
  w |= __shfl_xor(w, 8);
  if ((lane & 15) == 0) {
    int wordIdx = ((oy + ly) << 3) + tX;    // (row*512 + ox) / 64
    unsigned long long* dst = (img < 8) ? (bitsBG + ((img & 7) << 12))
                                        : (bitsFG + ((img & 7) << 12));
    dst[wordIdx] = w;
  }
}

// Pure-streaming CE, one thread per (p, b, float4-group): exactly 2 float4
// loads + 2 cached u64 bit-word loads per thread (all issued up front, tiny
// register footprint -> no serialized load chains), 6144 blocks for full TLP.
// Per-block partials to DISTINCT addresses (no same-line atomic contention);
// counts produced only by the p==0 blocks (uniform branch per block).
__global__ __launch_bounds__(256) void k_ce(const float* __restrict__ preds,
                                            const unsigned long long* __restrict__ bitsBG,
                                            const unsigned long long* __restrict__ bitsFG,
                                            float* __restrict__ pf,
                                            float* __restrict__ pbg,
                                            int* __restrict__ pcf,
                                            int* __restrict__ pcb) {
  int tid = blockIdx.x * 256 + threadIdx.x;   // [0, 3*8*65536)
  int g4  = tid & 65535;                      // float4 group within image
  int pb  = tid >> 16;                        // 0..23
  int b   = pb & 7;
  int p   = pb >> 3;                          // 0..2 (uniform per block)

  int wi = (b << 12) + (g4 >> 4);             // u64 word index
  int sh = (g4 & 15) << 2;                    // nibble shift within word
  unsigned nB = (unsigned)(bitsBG[wi] >> sh) & 15u;
  unsigned nF = (unsigned)(bitsFG[wi] >> sh) & 15u;

  const float* pbase = preds + ((size_t)((p * Bsz + b) * 2) << LOG2HW);
  int px = g4 << 2;
  float4 A0 = *(const float4*)&pbase[px];
  float4 A1 = *(const float4*)&pbase[HWv + px];

  float d[4] = {A0.x - A1.x, A0.y - A1.y, A0.z - A1.z, A0.w - A1.w};
  float sfg = 0.f, sbg = 0.f;
  #pragma unroll
  for (int j = 0; j < 4; ++j) {
    float sp = logf(1.f + expf(-fabsf(d[j])));
    bool vfj = (nF >> j) & 1u;
    bool vbj = !((nB >> j) & 1u);
    sfg += vfj ? (fmaxf(d[j], 0.f) + sp) : 0.f;
    sbg += vbj ? (fmaxf(-d[j], 0.f) + sp) : 0.f;
  }
  int cf = __popc(nF);
  int cb = 4 - __popc(nB);

  // block reduction: wave64 shuffle -> LDS -> one partial-write per block
  #pragma unroll
  for (int off = 32; off > 0; off >>= 1) {
    sfg += __shfl_down(sfg, off);
    sbg += __shfl_down(sbg, off);
    cf  += __shfl_down(cf, off);
    cb  += __shfl_down(cb, off);
  }
  __shared__ float lsf[4], lsb[4];
  __shared__ int   lcf[4], lcb[4];
  int wave = threadIdx.x >> 6;
  if ((threadIdx.x & 63) == 0) {
    lsf[wave] = sfg; lsb[wave] = sbg; lcf[wave] = cf; lcb[wave] = cb;
  }
  __syncthreads();
  if (threadIdx.x == 0) {
    pf[blockIdx.x]  = lsf[0] + lsf[1] + lsf[2] + lsf[3];
    pbg[blockIdx.x] = lsb[0] + lsb[1] + lsb[2] + lsb[3];
    if (p == 0) {                       // count each pixel ONCE (p==0 blocks)
      pcf[blockIdx.x] = lcf[0] + lcf[1] + lcf[2] + lcf[3];
      pcb[blockIdx.x] = lcb[0] + lcb[1] + lcb[2] + lcb[3];
    }
  }
}

// Final reduce: 6144x2 float partials + 2048x2 int partials in one block.
__global__ __launch_bounds__(1024) void k_final(const float* __restrict__ pf,
                                                const float* __restrict__ pbg,
                                                const int* __restrict__ pcf,
                                                const int* __restrict__ pcb,
                                                float* __restrict__ out) {
  int t = threadIdx.x;
  double sf = 0.0, sb = 0.0;
  int cf = 0, cb = 0;
  #pragma unroll
  for (int k = 0; k < CEBLK / 1024; ++k) {
    sf += (double)pf[k * 1024 + t];
    sb += (double)pbg[k * 1024 + t];
  }
  #pragma unroll
  for (int k = 0; k < CNTBLK / 1024; ++k) {
    cf += pcf[k * 1024 + t];
    cb += pcb[k * 1024 + t];
  }
  #pragma unroll
  for (int off = 32; off > 0; off >>= 1) {
    sf += __shfl_down(sf, off);
    sb += __shfl_down(sb, off);
    cf += __shfl_down(cf, off);
    cb += __shfl_down(cb, off);
  }
  __shared__ double dsf[16], dsb[16];
  __shared__ int    icf[16], icb[16];
  int wave = t >> 6;
  if ((t & 63) == 0) { dsf[wave] = sf; dsb[wave] = sb; icf[wave] = cf; icb[wave] = cb; }
  __syncthreads();
  if (t == 0) {
    double tf = 0.0, tb = 0.0; int af_ = 0, ab_ = 0;
    #pragma unroll
    for (int w = 0; w < 16; ++w) { tf += dsf[w]; tb += dsb[w]; af_ += icf[w]; ab_ += icb[w]; }
    double df = af_ > 0 ? (double)af_ : 1.0;
    double db = ab_ > 0 ? (double)ab_ : 1.0;
    out[0] = (float)(tf / df + tb / db);
  }
}

extern "C" void kernel_launch(void* const* d_in, const int* in_sizes, int n_in,
                              void* d_out, int out_size, void* d_ws, size_t ws_size,
                              hipStream_t stream) {
  (void)in_sizes; (void)n_in; (void)out_size; (void)ws_size;
  const float* preds = (const float*)d_in[0];  // [3,8,2,512,512] f32
  const float* cams  = (const float*)d_in[1];  // [8,1,512,512]  f32
  float* out = (float*)d_out;                  // scalar f32

  int* labels = (int*)d_ws;
  int* areas  = labels + NIMG * HWv;
  int* maxa   = areas + NIMG * HWv;
  double* sums = (double*)(maxa + 16);         // legacy slot (keeps alignment)
  int* counts  = (int*)(sums + 2);
  unsigned long long* bitsBG = (unsigned long long*)(counts + 2);  // 8-aligned
  unsigned long long* bitsFG = bitsBG + Bsz * (HWv / 64);          // 256 KB each
  float* pf  = (float*)(bitsFG + Bsz * (HWv / 64));
  float* pbg = pf + CEBLK;
  int*   pcf = (int*)(pbg + CEBLK);
  int*   pcb = pcf + CNTBLK;

  const int threads = 256;

  k_local  <<<NIMG * 64, 1024, 0, stream>>>(cams, labels, areas);
  k_border <<<(NIMG * 14 * Wdim + threads - 1) / threads, threads, 0, stream>>>(labels, maxa);
  k_flatten<<<NIMG * HWv / (threads * 4), threads, 0, stream>>>(labels, areas);
  k_max    <<<NIMG * 16, threads, 0, stream>>>(areas, maxa);
  k_verdict<<<NIMG * 64, 1024, 0, stream>>>(labels, areas, maxa, bitsBG, bitsFG);
  k_ce     <<<CEBLK, threads, 0, stream>>>(preds, bitsBG, bitsFG, pf, pbg, pcf, pcb);
  k_final  <<<1, 1024, 0, stream>>>(pf, pbg, pcf, pcb, out);
}